// Round 6
// baseline (107.232 us; speedup 1.0000x reference)
//
#include <hip/hip_runtime.h>

#define DEVI __device__ __forceinline__

typedef int i32x4 __attribute__((ext_vector_type(4)));

static constexpr int Bdim = 2048;
static constexpr int Kdim = 4096;
static constexpr int Ndim = 8192;
static constexpr int BK   = 128;         // int8 k-elements per tile (128 B/row)
static constexpr int NT   = Kdim / BK;   // 32 K-tiles

typedef __attribute__((address_space(1))) const unsigned int gas_t;
typedef __attribute__((address_space(3))) unsigned int las_t;
typedef __attribute__((address_space(3))) const char lds_cchar;

DEVI void gload_lds16(const void* g, void* l) {
    __builtin_amdgcn_global_load_lds((gas_t*)g, (las_t*)l, 16, 0, 0);
}

DEVI i32x4 dsread128(lds_cchar* p) {
    i32x4 r;
    asm volatile("ds_read_b128 %0, %1" : "=v"(r) : "v"(p));
    return r;
}

DEVI int pack4(i32x4 v) {
    return (v[0] & 255) | ((v[1] & 255) << 8) | ((v[2] & 255) << 16) | (v[3] << 24);
}

// ---------------- pack: int32 -> int8 ----------------
__global__ void pack_i32_to_i8(const int* __restrict__ in, char* __restrict__ out, int n16) {
    int i = blockIdx.x * blockDim.x + threadIdx.x;
    if (i >= n16) return;
    const i32x4* src = (const i32x4*)in + (size_t)i * 4;
    i32x4 r;
    r[0] = pack4(src[0]);
    r[1] = pack4(src[1]);
    r[2] = pack4(src[2]);
    r[3] = pack4(src[3]);
    ((i32x4*)out)[i] = r;
}

// ---------------- 256x256 8-phase i8 GEMM, frag-double-buffered ----------------
#define CFENCE asm volatile("" ::: "memory")
DEVI void bar() { CFENCE; __builtin_amdgcn_s_barrier(); CFENCE; }
#define WAITVM(N) asm volatile("s_waitcnt vmcnt(" #N ")" ::: "memory")
#define WAITLG(N) asm volatile("s_waitcnt lgkmcnt(" #N ")" ::: "memory")
#define SCHB __builtin_amdgcn_sched_barrier(0)
#define PRIO1 __builtin_amdgcn_s_setprio(1)
#define PRIO0 __builtin_amdgcn_s_setprio(0)

#define QX(MB, A, B)                                                             \
    do {                                                                         \
        _Pragma("unroll") for (int mm = 0; mm < 4; ++mm)                         \
        _Pragma("unroll") for (int n = 0; n < 4; ++n)                            \
            acc[(MB) + mm][n] = __builtin_amdgcn_mfma_i32_16x16x64_i8(           \
                (A)[mm], (B)[n], acc[(MB) + mm][n], 0, 0, 0);                    \
    } while (0)

// Phase p issues ds_reads for phase p+1's fragments (alt register bank), then
// counted lgkm proves only the OLDER (current-phase) reads. Waits W1/W2 force
// staged data present one phase before its reads issue (derivation in journal).
#define TILE(CUR, S1, S2, S3, S4, W1, W2, RD4S, LG4)                                        \
    {                                                                                       \
        rdP2(CUR); S1; bar(); WAITLG(4); SCHB; PRIO1; QX(0, a0, b0); PRIO0; W1; bar();      \
        rdP3(CUR); S2; bar(); WAITLG(8); SCHB; PRIO1; QX(4, a1, b0); PRIO0; bar();          \
        rdP4(CUR); S3; bar(); WAITLG(4); SCHB; PRIO1; QX(0, a0, b1); PRIO0; W2; bar();      \
        RD4S;      S4; bar(); LG4;       SCHB; PRIO1; QX(4, a1, b1); PRIO0; bar();          \
    }

__global__ __launch_bounds__(512, 2)
void gemm8(const char* __restrict__ A8, const char* __restrict__ B8,
           const int* __restrict__ bias,
           const int* __restrict__ qm_p, const int* __restrict__ ex_p,
           const int* __restrict__ zp_p, int* __restrict__ out) {
    // LDS: A [2 buf][2 ks][256 rows][64 B] at 0, B same at 65536 -> 128 KiB
    __shared__ __align__(16) char smem[131072];
    lds_cchar* sbase = (lds_cchar*)smem;

    const int tid  = threadIdx.x;
    const int wid  = tid >> 6;
    const int lane = tid & 63;
    const int l15  = lane & 15;
    const int lks  = lane >> 4;
    const int wr   = wid >> 2;   // 0..1
    const int wc   = wid & 3;    // 0..3

    // XCD swizzle: 256 blocks, each XCD gets one bm stripe
    const int bid = blockIdx.x;
    const int swz = (bid & 7) * 32 + (bid >> 3);
    const int bm  = swz >> 5;    // 0..7
    const int bn  = swz & 31;    // 0..31
    const int arow0 = bm * 256;
    const int brow0 = bn * 256;

    // T2 swizzle: phys_slot = chunk ^ ((row>>1)&3); row bases 16-aligned =>
    // fragment-read selector depends only on (l15>>1)&3
    const int sw16 = (lks ^ ((l15 >> 1) & 3)) * 16;
    const int a_rd = (wr * 128 + l15) * 64 + sw16;
    const int b_rd = 65536 + (wc * 64 + l15) * 64 + sw16;

    // stage addressing: thread covers (row = tid>>2 [+128], chunk = st_c)
    const int st_c = (tid & 3) ^ ((tid >> 3) & 3);
    const char* agp = A8 + (size_t)(arow0 + (tid >> 2)) * Kdim + st_c * 16;
    const char* bgp = B8 + (size_t)(brow0 + (tid >> 2)) * Kdim + st_c * 16;

    auto stage = [&](int isb, int t, int ks) {
        const char* gp = (isb ? bgp : agp) + (size_t)t * BK + ks * 64;
        const int lb = (isb ? 65536 : 0) + (t & 1) * 32768 + ks * 16384 + tid * 16;
        gload_lds16(gp, &smem[lb]);
        gload_lds16(gp + (size_t)128 * Kdim, &smem[lb + 8192]);
    };

    i32x4 acc[8][4] = {};
    i32x4 a0[4], a1[4], b0[4], b1[4];

    // fragment-read lambdas: rdP{k} loads the frags PHASE k consumes
    auto rdP1 = [&](int buf) {   // a0 = A.ks0 rows 0-63 of half, b0 = B.ks0
#pragma unroll
        for (int m = 0; m < 4; ++m)
            a0[m] = dsread128(sbase + (buf * 32768 + a_rd + m * 1024));
#pragma unroll
        for (int n = 0; n < 4; ++n)
            b0[n] = dsread128(sbase + (buf * 32768 + b_rd + n * 1024));
    };
    auto rdP2 = [&](int buf) {   // a1 = A.ks0 rows 64-127 of half
#pragma unroll
        for (int m = 0; m < 4; ++m)
            a1[m] = dsread128(sbase + (buf * 32768 + a_rd + (4 + m) * 1024));
    };
    auto rdP3 = [&](int buf) {   // a0 = A.ks1 h0, b1 = B.ks1
#pragma unroll
        for (int m = 0; m < 4; ++m)
            a0[m] = dsread128(sbase + (buf * 32768 + 16384 + a_rd + m * 1024));
#pragma unroll
        for (int n = 0; n < 4; ++n)
            b1[n] = dsread128(sbase + (buf * 32768 + 16384 + b_rd + n * 1024));
    };
    auto rdP4 = [&](int buf) {   // a1 = A.ks1 h1
#pragma unroll
        for (int m = 0; m < 4; ++m)
            a1[m] = dsread128(sbase + (buf * 32768 + 16384 + a_rd + (4 + m) * 1024));
    };

    // prologue stages, ring order: S2(-2) S3(-2) S4(-2) S1(-1) S2(-1) S3(-1) S4(-1)
    stage(1, 0, 0); stage(0, 0, 0); stage(1, 0, 1); stage(0, 0, 1);
    stage(1, 1, 0); stage(0, 1, 0); stage(1, 1, 1);
    WAITVM(10);          // proves (0).B.ks0 and (0).A.ks0 landed
    bar();
    rdP1(0);             // tile-0 phase-1 fragments

    int cur = 0;
    for (int t = 0; t < NT - 2; ++t) {   // t = 0..29
        TILE(cur,
             stage(0, t + 1, 1),         // S1 -> (t+1).A.ks1
             stage(1, t + 2, 0),         // S2 -> (t+2).B.ks0
             stage(0, t + 2, 0),         // S3 -> (t+2).A.ks0
             stage(1, t + 2, 1),         // S4 -> (t+2).B.ks1
             WAITVM(8), WAITVM(8),
             rdP1(cur ^ 1), WAITLG(8));
        cur ^= 1;
    }
    // t = NT-2: only S1 valid; W2 proves S3(NT-3) with 4 newer instrs
    TILE(cur,
         stage(0, NT - 1, 1),
         ((void)0), ((void)0), ((void)0),
         WAITVM(8), WAITVM(4),
         rdP1(cur ^ 1), WAITLG(8));
    cur ^= 1;
    // t = NT-1: no stages, no P4 prefetch reads
    TILE(cur,
         ((void)0), ((void)0), ((void)0), ((void)0),
         WAITVM(0), ((void)0),
         ((void)0), WAITLG(0));

    // ---------------- epilogue: requantize ----------------
    const int qm = *qm_p;
    const int ex = *ex_p;
    const int zp = *zp_p;
    const int rm = (qm < 2147418112) ? ((qm + (1 << 15)) >> 16) : 32767;
    const int shifts = 15 - ex;
    const long long rnd = (shifts > 0) ? (1LL << (shifts - 1)) : 0;

    int bv[4];
#pragma unroll
    for (int n = 0; n < 4; ++n) bv[n] = bias[brow0 + wc * 64 + n * 16 + l15];

#pragma unroll
    for (int m = 0; m < 8; ++m) {
        const int row0 = arow0 + wr * 128 + m * 16 + lks * 4;
#pragma unroll
        for (int n = 0; n < 4; ++n) {
            const int col = brow0 + wc * 64 + n * 16 + l15;
#pragma unroll
            for (int j = 0; j < 4; ++j) {
                long long t = (long long)(acc[m][n][j] + bv[n]) * rm + rnd;
                t >>= shifts;
                t += zp;
                t = t < -128 ? -128 : (t > 127 ? 127 : t);
                out[(size_t)(row0 + j) * Ndim + col] = (int)t;
            }
        }
    }
}

extern "C" void kernel_launch(void* const* d_in, const int* in_sizes, int n_in,
                              void* d_out, int out_size, void* d_ws, size_t ws_size,
                              hipStream_t stream) {
    const int* x32  = (const int*)d_in[0];
    const int* w32  = (const int*)d_in[1];
    const int* bias = (const int*)d_in[2];
    const int* qm   = (const int*)d_in[3];
    const int* ex   = (const int*)d_in[4];
    const int* zp   = (const int*)d_in[5];
    int* out = (int*)d_out;

    char* xa = (char*)d_ws;
    char* wa = xa + (size_t)Bdim * Kdim;
    const int nx16 = Bdim * Kdim / 16;   // 524288
    const int nw16 = Ndim * Kdim / 16;   // 2097152
    pack_i32_to_i8<<<(nx16 + 255) / 256, 256, 0, stream>>>(x32, xa, nx16);
    pack_i32_to_i8<<<(nw16 + 255) / 256, 256, 0, stream>>>(w32, wa, nw16);

    const int grid = (Bdim / 256) * (Ndim / 256);   // 8 * 32 = 256
    gemm8<<<grid, 512, 0, stream>>>(xa, wa, bias, qm, ex, zp, out);
}